// Round 2
// baseline (572.304 us; speedup 1.0000x reference)
//
#include <hip/hip_runtime.h>
#include <math.h>

// ---------------------------------------------------------------------------
// GCN 5-layer forward, dinv-prescaled formulation.
//   agg[v] = dinv[v] * ( sum_{s in N(v)} hs[s] + hs[v] ),  hs = dinv (.) h.
// Layer plan (narrow-side aggregation, chunk-major intermediates):
//   L1: agg2(xs=dinv*x) -> gemm 2->128 +b1 relu *dinv
//   L2: gemm 128->128 (cm32 out) ; agg128x +b2 relu *dinv (cm32)
//   L3: gemm 128->32 (cm32 in, cm8 out) ; agg32x +b3 relu *dinv (cm8)
//   L4: gemm 32->32 (cm8 in/out) ; agg32x +b4 relu *dinv (cm8)
//   L5: agg32x raw (cm8) ; gemm_final (cm8 in): (t5@W5+b5).relu @ Wl + bl
// R15: agg32 -> agg32x: 8 XCD-pinned classes = (8-col chunk x dst-half),
//   h chunk-major [4][N][8]. Slice = 3.2 MB -> L2-RESIDENT (R14 lesson: the
//   12.8 MB agg128x slice was 3.2x L2, hit only ~64%). Per-edge granule 32 B
//   (8 lanes x 4 B scalar loads, shuffle machinery unchanged, accumulation
//   order bitwise-identical). csr tax 8 x 3.2 = 25.6 MB. Predicted fetch
//   ~110 -> ~60 MB, dur 45 -> ~22-27us per agg32x.
// R14 post-mortem: agg128x 127->98us, FETCH 414->328 MB. Slicing works but
//   12.8 MB slice >> 4 MB L2 limits hit to ~64%. Going finer (16x8-col)
//   costs 102 MB csr re-reads + 25.6M segment requests -> left as-is.
// R13 post-mortem: gemm_big128 spilled accumulators. REVERTED.
// Structural walls (measured): agg128x ~98us; fill/count atomic floors;
//   fp32 vector-ALU gemms (no fp32 MFMA; bf16 blows the 7.9e-5 budget).
// ---------------------------------------------------------------------------

static inline int cdiv(int a, int b) { return (a + b - 1) / b; }

__global__ void zero_i32(int* __restrict__ p, int n) {
    int i = blockIdx.x * 256 + threadIdx.x;
    if (i < n) p[i] = 0;
}

// Plain 1-pass degree count: atomics, no line-ownership migration.
__global__ void count_kernel(const int* __restrict__ dst, int* __restrict__ cnt, int E) {
    int e = blockIdx.x * 256 + threadIdx.x;
    if (e < E) atomicAdd(&cnt[dst[e]], 1);
}

// Inclusive scan per 256-block; inclusive partials to off, block totals to bsum.
__global__ void scan1(const int* __restrict__ cnt, int* __restrict__ off,
                      int* __restrict__ bsum, int n) {
    __shared__ int sm[256];
    int i = blockIdx.x * 256 + threadIdx.x;
    int v = (i < n) ? cnt[i] : 0;
    sm[threadIdx.x] = v;
    __syncthreads();
    for (int ofs = 1; ofs < 256; ofs <<= 1) {
        int t = (threadIdx.x >= (unsigned)ofs) ? sm[threadIdx.x - ofs] : 0;
        __syncthreads();
        sm[threadIdx.x] += t;
        __syncthreads();
    }
    if (i < n) off[i] = sm[threadIdx.x];
    if (threadIdx.x == 255) bsum[blockIdx.x] = sm[255];
}

// Exclusive scan of block sums (nb <= 512).
__global__ void scan2(const int* __restrict__ bsum, int* __restrict__ bpre,
                      int nb, int* __restrict__ off, int N, int E) {
    __shared__ int sm[512];
    int t = threadIdx.x;
    sm[t] = (t < nb) ? bsum[t] : 0;
    __syncthreads();
    for (int ofs = 1; ofs < 512; ofs <<= 1) {
        int v = (t >= ofs) ? sm[t - ofs] : 0;
        __syncthreads();
        sm[t] += v;
        __syncthreads();
    }
    if (t < nb) bpre[t] = sm[t] - bsum[t];
    if (t == 0) off[N] = E;
}

// Fused: finalize off (exclusive), seed cursor=off, dinv=1/sqrt(deg+1),
// xs = dinv * x (pre-scaled layer-1 input).
__global__ void scan3_fused(const int* __restrict__ cnt, const int* __restrict__ bpre,
                            int* __restrict__ off, int* __restrict__ cursor,
                            const float* __restrict__ x, float* __restrict__ dinv,
                            float* __restrict__ xs, int n) {
    int i = blockIdx.x * 256 + threadIdx.x;
    if (i < n) {
        int c = cnt[i];
        int o = off[i] - c + bpre[blockIdx.x];
        off[i] = o;
        cursor[i] = o;
        float dv = 1.0f / sqrtf((float)c + 1.0f);
        dinv[i] = dv;
        float2 xv = *reinterpret_cast<const float2*>(x + 2 * (size_t)i);
        *reinterpret_cast<float2*>(xs + 2 * (size_t)i) = float2{dv * xv.x, dv * xv.y};
    }
}

// XCD-class-filtered CSR fill: class c handles only its dst-range, so its
// cursor slice (~50 KB) and csr slice (~800 KB) stay in one XCD's L2.
__global__ __launch_bounds__(256) void fill_ranged(const int* __restrict__ src,
                                                   const int* __restrict__ dst,
                                                   int* __restrict__ cursor,
                                                   int* __restrict__ csr,
                                                   int E, int N, int echunk) {
    int cls = blockIdx.x & 7;
    int chunk = blockIdx.x >> 3;
    int per = (N + 7) >> 3;
    int lo = cls * per;
    int hi = lo + per; if (hi > N) hi = N;
    int e0 = chunk * echunk;
    int e1 = e0 + echunk; if (e1 > E) e1 = E;
    for (int e = e0 + (int)threadIdx.x; e < e1; e += 256) {
        int d = dst[e];
        if (d >= lo && d < hi) {
            int p = atomicAdd(&cursor[d], 1);
            csr[p] = src[e];
        }
    }
}

// ---------------------------------------------------------------------------
// Aggregation of pre-scaled [N,2] input: one thread per node.
// ---------------------------------------------------------------------------
__global__ __launch_bounds__(256) void agg2_kernel(const float* __restrict__ xs,
                                                   const int* __restrict__ off,
                                                   const int* __restrict__ csr,
                                                   const float* __restrict__ dinv,
                                                   float* __restrict__ out, int n) {
    int v = blockIdx.x * 256 + threadIdx.x;
    if (v >= n) return;
    float a0 = 0.f, a1 = 0.f;
    int e0 = off[v], e1 = off[v + 1];
    for (int e = e0; e < e1; e++) {
        int s = csr[e];
        float2 q = *reinterpret_cast<const float2*>(xs + 2 * (size_t)s);
        a0 += q.x;
        a1 += q.y;
    }
    float dv = dinv[v];
    float2 xv = *reinterpret_cast<const float2*>(xs + 2 * (size_t)v);
    *reinterpret_cast<float2*>(out + 2 * (size_t)v) =
        float2{dv * (a0 + xv.x), dv * (a1 + xv.y)};
}

// ---------------------------------------------------------------------------
// agg128x: F=128 aggregation, XCD-sliced. h is chunk-major hc[4][N][32].
// class = blockIdx&7: chunk = cls>>1 (32-col slice), half = cls&1 (dst half).
// 12.8 MB slice per XCD (1 L2's reach), per-edge granule = 128 B.
// ---------------------------------------------------------------------------
template <bool BR, bool PS>
__global__ __launch_bounds__(256) void agg128x_kernel(const float* __restrict__ hc,
                                                      const int* __restrict__ off,
                                                      const int* __restrict__ csr,
                                                      const float* __restrict__ dinv,
                                                      const float* __restrict__ bias,
                                                      float* __restrict__ outc, int n) {
    int cls = blockIdx.x & 7;
    int chunk = cls >> 1;
    int half = cls & 1;
    int n2 = (n + 1) >> 1;
    int lo = half * n2;
    int hi = lo + n2; if (hi > n) hi = n;

    const float* __restrict__ h = hc + (size_t)chunk * n * 32;
    float* __restrict__ out = outc + (size_t)chunk * n * 32;

    int tid = threadIdx.x;
    int lane = tid & 63;
    int sl = lane & 7;
    int subbase = lane & ~7;
    int wave = tid >> 6;
    int v = lo + (blockIdx.x >> 3) * 32 + wave * 8 + (lane >> 3);
    if (v >= hi) return;

    int start = off[v];
    int end = off[v + 1];

    float4 acc = {0.f, 0.f, 0.f, 0.f};

    for (int base = start; base < end; base += 16) {
        int m = end - base;
        if (m > 16) m = 16;
        int idxA = (sl < m) ? csr[base + sl] : 0;
        int idxB = (8 + sl < m) ? csr[base + 8 + sl] : 0;
        if (m == 16) {
            float4 hb[16];
#pragma unroll
            for (int u = 0; u < 16; u++) {
                int s = __shfl((u < 8) ? idxA : idxB, subbase + (u & 7));
                hb[u] = *reinterpret_cast<const float4*>(h + (size_t)s * 32 + sl * 4);
            }
#pragma unroll
            for (int u = 0; u < 16; u++) {
                acc.x += hb[u].x; acc.y += hb[u].y; acc.z += hb[u].z; acc.w += hb[u].w;
            }
        } else {
            int ma = (m < 8) ? m : 8;
            int i = 0;
            for (; i + 4 <= ma; i += 4) {
                float4 hb[4];
#pragma unroll
                for (int u = 0; u < 4; u++) {
                    int s = __shfl(idxA, subbase + i + u);
                    hb[u] = *reinterpret_cast<const float4*>(h + (size_t)s * 32 + sl * 4);
                }
#pragma unroll
                for (int u = 0; u < 4; u++) {
                    acc.x += hb[u].x; acc.y += hb[u].y; acc.z += hb[u].z; acc.w += hb[u].w;
                }
            }
            if (i + 2 <= ma) {
                int s0 = __shfl(idxA, subbase + i);
                int s1 = __shfl(idxA, subbase + i + 1);
                float4 h0 = *reinterpret_cast<const float4*>(h + (size_t)s0 * 32 + sl * 4);
                float4 h1 = *reinterpret_cast<const float4*>(h + (size_t)s1 * 32 + sl * 4);
                acc.x += h0.x + h1.x; acc.y += h0.y + h1.y;
                acc.z += h0.z + h1.z; acc.w += h0.w + h1.w;
                i += 2;
            }
            if (i < ma) {
                int s0 = __shfl(idxA, subbase + i);
                float4 h0 = *reinterpret_cast<const float4*>(h + (size_t)s0 * 32 + sl * 4);
                acc.x += h0.x; acc.y += h0.y; acc.z += h0.z; acc.w += h0.w;
            }
            if (m > 8) {
                int mb = m - 8;
                int j = 0;
                for (; j + 4 <= mb; j += 4) {
                    float4 hb[4];
#pragma unroll
                    for (int u = 0; u < 4; u++) {
                        int s = __shfl(idxB, subbase + j + u);
                        hb[u] = *reinterpret_cast<const float4*>(h + (size_t)s * 32 + sl * 4);
                    }
#pragma unroll
                    for (int u = 0; u < 4; u++) {
                        acc.x += hb[u].x; acc.y += hb[u].y; acc.z += hb[u].z; acc.w += hb[u].w;
                    }
                }
                if (j + 2 <= mb) {
                    int s0 = __shfl(idxB, subbase + j);
                    int s1 = __shfl(idxB, subbase + j + 1);
                    float4 h0 = *reinterpret_cast<const float4*>(h + (size_t)s0 * 32 + sl * 4);
                    float4 h1 = *reinterpret_cast<const float4*>(h + (size_t)s1 * 32 + sl * 4);
                    acc.x += h0.x + h1.x; acc.y += h0.y + h1.y;
                    acc.z += h0.z + h1.z; acc.w += h0.w + h1.w;
                    j += 2;
                }
                if (j < mb) {
                    int s0 = __shfl(idxB, subbase + j);
                    float4 h0 = *reinterpret_cast<const float4*>(h + (size_t)s0 * 32 + sl * 4);
                    acc.x += h0.x; acc.y += h0.y; acc.z += h0.z; acc.w += h0.w;
                }
            }
        }
    }

    float dv = dinv[v];
    float4 hv = *reinterpret_cast<const float4*>(h + (size_t)v * 32 + sl * 4);
    float o0 = dv * (acc.x + hv.x);
    float o1 = dv * (acc.y + hv.y);
    float o2 = dv * (acc.z + hv.z);
    float o3 = dv * (acc.w + hv.w);
    if constexpr (BR) {
        float4 b = *reinterpret_cast<const float4*>(bias + chunk * 32 + sl * 4);
        o0 = fmaxf(o0 + b.x, 0.f);
        o1 = fmaxf(o1 + b.y, 0.f);
        o2 = fmaxf(o2 + b.z, 0.f);
        o3 = fmaxf(o3 + b.w, 0.f);
    }
    if constexpr (PS) {
        o0 *= dv; o1 *= dv; o2 *= dv; o3 *= dv;
    }
    *reinterpret_cast<float4*>(out + (size_t)v * 32 + sl * 4) = float4{o0, o1, o2, o3};
}

// ---------------------------------------------------------------------------
// agg32x: F=32 aggregation, XCD-sliced with L2-RESIDENT slices.
// h chunk-major [4][N][8]; class = blockIdx&7: chunk = cls>>1 (8 cols,
// slice = 3.2 MB <= L2), half = cls&1 (dst half). 8 lanes/node, each lane
// owns ONE column (scalar 4 B load; group = one 32 B segment/edge).
// Shuffle structure identical to the tuned agg32; accumulation order per
// column bitwise-identical (absmax-neutral).
// ---------------------------------------------------------------------------
template <bool BR, bool PS>
__global__ __launch_bounds__(256) void agg32x_kernel(const float* __restrict__ hc,
                                                     const int* __restrict__ off,
                                                     const int* __restrict__ csr,
                                                     const float* __restrict__ dinv,
                                                     const float* __restrict__ bias,
                                                     float* __restrict__ outc, int n) {
    int cls = blockIdx.x & 7;
    int chunk = cls >> 1;
    int half = cls & 1;
    int n2 = (n + 1) >> 1;
    int lo = half * n2;
    int hi = lo + n2; if (hi > n) hi = n;

    const float* __restrict__ h = hc + (size_t)chunk * n * 8;
    float* __restrict__ out = outc + (size_t)chunk * n * 8;

    int tid = threadIdx.x;
    int lane = tid & 63;
    int sl = lane & 7;
    int subbase = lane & ~7;
    int wave = tid >> 6;
    int v = lo + (blockIdx.x >> 3) * 32 + wave * 8 + (lane >> 3);
    if (v >= hi) return;

    int start = off[v];
    int end = off[v + 1];

    float acc = 0.f;

    for (int base = start; base < end; base += 16) {
        int m = end - base;
        if (m > 16) m = 16;
        int idxA = (sl < m) ? csr[base + sl] : 0;
        int idxB = (8 + sl < m) ? csr[base + 8 + sl] : 0;
        if (m == 16) {
            float hb[16];
#pragma unroll
            for (int u = 0; u < 16; u++) {
                int s = __shfl((u < 8) ? idxA : idxB, subbase + (u & 7));
                hb[u] = h[(size_t)s * 8 + sl];
            }
#pragma unroll
            for (int u = 0; u < 16; u++) acc += hb[u];
        } else {
            int ma = (m < 8) ? m : 8;
            int i = 0;
            for (; i + 4 <= ma; i += 4) {
                float hb[4];
#pragma unroll
                for (int u = 0; u < 4; u++) {
                    int s = __shfl(idxA, subbase + i + u);
                    hb[u] = h[(size_t)s * 8 + sl];
                }
#pragma unroll
                for (int u = 0; u < 4; u++) acc += hb[u];
            }
            if (i + 2 <= ma) {
                int s0 = __shfl(idxA, subbase + i);
                int s1 = __shfl(idxA, subbase + i + 1);
                acc += h[(size_t)s0 * 8 + sl] + h[(size_t)s1 * 8 + sl];
                i += 2;
            }
            if (i < ma) {
                int s0 = __shfl(idxA, subbase + i);
                acc += h[(size_t)s0 * 8 + sl];
            }
            if (m > 8) {
                int mb = m - 8;
                int j = 0;
                for (; j + 4 <= mb; j += 4) {
                    float hb[4];
#pragma unroll
                    for (int u = 0; u < 4; u++) {
                        int s = __shfl(idxB, subbase + j + u);
                        hb[u] = h[(size_t)s * 8 + sl];
                    }
#pragma unroll
                    for (int u = 0; u < 4; u++) acc += hb[u];
                }
                if (j + 2 <= mb) {
                    int s0 = __shfl(idxB, subbase + j);
                    int s1 = __shfl(idxB, subbase + j + 1);
                    acc += h[(size_t)s0 * 8 + sl] + h[(size_t)s1 * 8 + sl];
                    j += 2;
                }
                if (j < mb) {
                    int s0 = __shfl(idxB, subbase + j);
                    acc += h[(size_t)s0 * 8 + sl];
                }
            }
        }
    }

    float dv = dinv[v];
    float hv = h[(size_t)v * 8 + sl];
    float o = dv * (acc + hv);
    if constexpr (BR) {
        o = fmaxf(o + bias[chunk * 8 + sl], 0.f);
    }
    if constexpr (PS) {
        o *= dv;
    }
    out[(size_t)v * 8 + sl] = o;
}

// ---------------------------------------------------------------------------
// Register-tiled GEMM: h[N,F] = x[N,K] @ W[K,F]; epilogue +bias/relu (BR),
// *dinv[row] (PS). KC=32 (KCP=36 breaks pow-2 banks): K=128 -> 4 chunks,
// K=32 -> single chunk (2 barriers).
// CIN/COUT: 0 = row-major, 32 = chunk-major [F/32][N][32] (agg128x),
// 8 = chunk-major [F/8][N][8] (agg32x). Both preserve coalesced stage/store
// (kk and cb are 8/4-aligned within 8-col chunks).
// ---------------------------------------------------------------------------
template <int K, int F, bool BR, bool PS, int CIN = 0, int COUT = 0>
__global__ __launch_bounds__(256, 4) void gemm_tiled(const float* __restrict__ x,
                                                     const float* __restrict__ W,
                                                     const float* __restrict__ bias,
                                                     const float* __restrict__ dinv,
                                                     float* __restrict__ h, int n) {
    constexpr int KC = 32;
    constexpr int KCP = 36;             // padded row stride (144 B, 16B-aligned)
    constexpr int ROWS = 64;
    constexpr int TPC = F / 4;
    constexpr int RT = 256 / TPC;
    constexpr int RPT = ROWS / RT;
    static_assert(K % KC == 0, "K must be a multiple of 32");

    __shared__ float Ws[KC * F];
    __shared__ float Xs[ROWS * KCP];

    const int tid = threadIdx.x;
    const int cb = (tid % TPC) * 4;
    const int tr = tid / TPC;
    const int row0 = blockIdx.x * ROWS;

    float acc[RPT][4];
#pragma unroll
    for (int r = 0; r < RPT; r++)
#pragma unroll
        for (int j = 0; j < 4; j++) acc[r][j] = 0.f;

#pragma unroll 1
    for (int k0 = 0; k0 < K; k0 += KC) {
        __syncthreads();
        {
            // Stage x chunk: 64 rows x 32 cols; thread -> row tid>>2, 8 cols.
            int r = tid >> 2;
            int kk = (tid & 3) * 8;
            int gr = row0 + r;
            float4 v0 = {0.f, 0.f, 0.f, 0.f}, v1 = {0.f, 0.f, 0.f, 0.f};
            if (gr < n) {
                if constexpr (CIN == 32) {
                    const float* xb = x + (size_t)(k0 >> 5) * n * 32 + (size_t)gr * 32 + kk;
                    v0 = *reinterpret_cast<const float4*>(xb);
                    v1 = *reinterpret_cast<const float4*>(xb + 4);
                } else if constexpr (CIN == 8) {
                    const float* xb = x + (size_t)((k0 + kk) >> 3) * n * 8 + (size_t)gr * 8;
                    v0 = *reinterpret_cast<const float4*>(xb);
                    v1 = *reinterpret_cast<const float4*>(xb + 4);
                } else {
                    v0 = *reinterpret_cast<const float4*>(x + (size_t)gr * K + k0 + kk);
                    v1 = *reinterpret_cast<const float4*>(x + (size_t)gr * K + k0 + kk + 4);
                }
            }
            *reinterpret_cast<float4*>(&Xs[r * KCP + kk]) = v0;
            *reinterpret_cast<float4*>(&Xs[r * KCP + kk + 4]) = v1;
        }
        for (int i = tid; i < KC * F / 4; i += 256) {
            *reinterpret_cast<float4*>(&Ws[i * 4]) =
                *reinterpret_cast<const float4*>(W + (size_t)k0 * F + i * 4);
        }
        __syncthreads();

#pragma unroll 4
        for (int kk4 = 0; kk4 < KC; kk4 += 4) {
            float4 xr[RPT];
#pragma unroll
            for (int r = 0; r < RPT; r++)
                xr[r] = *reinterpret_cast<const float4*>(&Xs[(tr * RPT + r) * KCP + kk4]);
#pragma unroll
            for (int j = 0; j < 4; j++) {
                float4 w = *reinterpret_cast<const float4*>(&Ws[(kk4 + j) * F + cb]);
#pragma unroll
                for (int r = 0; r < RPT; r++) {
                    float xv = (j == 0) ? xr[r].x : (j == 1) ? xr[r].y
                             : (j == 2) ? xr[r].z : xr[r].w;
                    acc[r][0] += xv * w.x;
                    acc[r][1] += xv * w.y;
                    acc[r][2] += xv * w.z;
                    acc[r][3] += xv * w.w;
                }
            }
        }
    }

    float4 b = float4{0.f, 0.f, 0.f, 0.f};
    if constexpr (BR) b = *reinterpret_cast<const float4*>(bias + cb);
#pragma unroll
    for (int r = 0; r < RPT; r++) {
        int row = row0 + tr * RPT + r;
        if (row < n) {
            float o0 = acc[r][0], o1 = acc[r][1], o2 = acc[r][2], o3 = acc[r][3];
            if constexpr (BR) {
                o0 = fmaxf(o0 + b.x, 0.f);
                o1 = fmaxf(o1 + b.y, 0.f);
                o2 = fmaxf(o2 + b.z, 0.f);
                o3 = fmaxf(o3 + b.w, 0.f);
            }
            if constexpr (PS) {
                float dv = dinv[row];
                o0 *= dv; o1 *= dv; o2 *= dv; o3 *= dv;
            }
            if constexpr (COUT == 32) {
                float* hb = h + (size_t)(cb >> 5) * n * 32 + (size_t)row * 32 + (cb & 31);
                *reinterpret_cast<float4*>(hb) = float4{o0, o1, o2, o3};
            } else if constexpr (COUT == 8) {
                float* hb = h + (size_t)(cb >> 3) * n * 8 + (size_t)row * 8 + (cb & 7);
                *reinterpret_cast<float4*>(hb) = float4{o0, o1, o2, o3};
            } else {
                *reinterpret_cast<float4*>(&h[(size_t)row * F + cb]) = float4{o0, o1, o2, o3};
            }
        }
    }
}

// ---------------------------------------------------------------------------
// Fused L5 + final: out[v] = relu(t5[v]@W5 + b5) . Wl + bl.  K=32, F=64.
// Input x is chunk-major [4][N][8] (from agg32x). Single KC=32 chunk; row
// outputs in 16 lanes x 4 regs -> dot with Wl (LDS) then 4-step shfl-xor
// reduce; lane0-of-16 writes out[row].
// ---------------------------------------------------------------------------
__global__ __launch_bounds__(256, 4) void gemm_final(const float* __restrict__ x,
                                                     const float* __restrict__ W,
                                                     const float* __restrict__ bias,
                                                     const float* __restrict__ Wl,
                                                     const float* __restrict__ bl,
                                                     float* __restrict__ out, int n) {
    constexpr int K = 32, F = 64;
    constexpr int KC = 32;
    constexpr int KCP = 36;
    constexpr int ROWS = 64;
    constexpr int TPC = F / 4;          // 16
    constexpr int RT = 256 / TPC;       // 16
    constexpr int RPT = ROWS / RT;      // 4

    __shared__ float Ws[KC * F];
    __shared__ float Xs[ROWS * KCP];
    __shared__ float wl[F];

    const int tid = threadIdx.x;
    if (tid < F) wl[tid] = Wl[tid];
    const int cb = (tid % TPC) * 4;
    const int tr = tid / TPC;
    const int row0 = blockIdx.x * ROWS;

    float acc[RPT][4];
#pragma unroll
    for (int r = 0; r < RPT; r++)
#pragma unroll
        for (int j = 0; j < 4; j++) acc[r][j] = 0.f;

    {
        {
            int r = tid >> 2;
            int kk = (tid & 3) * 8;
            int gr = row0 + r;
            float4 v0 = {0.f, 0.f, 0.f, 0.f}, v1 = {0.f, 0.f, 0.f, 0.f};
            if (gr < n) {
                const float* xb = x + (size_t)(kk >> 3) * n * 8 + (size_t)gr * 8;
                v0 = *reinterpret_cast<const float4*>(xb);
                v1 = *reinterpret_cast<const float4*>(xb + 4);
            }
            *reinterpret_cast<float4*>(&Xs[r * KCP + kk]) = v0;
            *reinterpret_cast<float4*>(&Xs[r * KCP + kk + 4]) = v1;
        }
        for (int i = tid; i < KC * F / 4; i += 256) {
            *reinterpret_cast<float4*>(&Ws[i * 4]) =
                *reinterpret_cast<const float4*>(W + i * 4);
        }
        __syncthreads();

#pragma unroll 4
        for (int kk4 = 0; kk4 < KC; kk4 += 4) {
            float4 xr[RPT];
#pragma unroll
            for (int r = 0; r < RPT; r++)
                xr[r] = *reinterpret_cast<const float4*>(&Xs[(tr * RPT + r) * KCP + kk4]);
#pragma unroll
            for (int j = 0; j < 4; j++) {
                float4 w = *reinterpret_cast<const float4*>(&Ws[(kk4 + j) * F + cb]);
#pragma unroll
                for (int r = 0; r < RPT; r++) {
                    float xv = (j == 0) ? xr[r].x : (j == 1) ? xr[r].y
                             : (j == 2) ? xr[r].z : xr[r].w;
                    acc[r][0] += xv * w.x;
                    acc[r][1] += xv * w.y;
                    acc[r][2] += xv * w.z;
                    acc[r][3] += xv * w.w;
                }
            }
        }
    }

    float4 b = *reinterpret_cast<const float4*>(bias + cb);
    float4 w = *reinterpret_cast<const float4*>(&wl[cb]);
    float blv = bl[0];
#pragma unroll
    for (int r = 0; r < RPT; r++) {
        int row = row0 + tr * RPT + r;
        float o0 = fmaxf(acc[r][0] + b.x, 0.f);
        float o1 = fmaxf(acc[r][1] + b.y, 0.f);
        float o2 = fmaxf(acc[r][2] + b.z, 0.f);
        float o3 = fmaxf(acc[r][3] + b.w, 0.f);
        float partial = o0 * w.x + o1 * w.y + o2 * w.z + o3 * w.w;
        partial += __shfl_xor(partial, 8, 16);
        partial += __shfl_xor(partial, 4, 16);
        partial += __shfl_xor(partial, 2, 16);
        partial += __shfl_xor(partial, 1, 16);
        if ((tid & 15) == 0 && row < n) out[row] = partial + blv;
    }
}

// Simple GEMM for K=2 (layer 1), epilogue +bias/relu (BR), *dinv (PS).
template <int K, int F, bool BR, bool PS>
__global__ __launch_bounds__(256, 4) void gemm_small(const float* __restrict__ x,
                                                     const float* __restrict__ W,
                                                     const float* __restrict__ bias,
                                                     const float* __restrict__ dinv,
                                                     float* __restrict__ h, int n) {
    constexpr int TPR = F / 4;
    constexpr int ROWS = 256 / TPR;
    __shared__ float Ws[K * F];
    for (int i = threadIdx.x; i < K * F; i += 256) Ws[i] = W[i];
    __syncthreads();

    int tid = threadIdx.x;
    int cb = (tid % TPR) * 4;
    int r = blockIdx.x * ROWS + tid / TPR;
    if (r >= n) return;

    const float* xr = x + (size_t)r * K;
    float a0 = 0.f, a1 = 0.f, a2 = 0.f, a3 = 0.f;
#pragma unroll
    for (int k = 0; k < K; k++) {
        float xv = xr[k];
        float4 w = *reinterpret_cast<const float4*>(&Ws[k * F + cb]);
        a0 += xv * w.x; a1 += xv * w.y; a2 += xv * w.z; a3 += xv * w.w;
    }
    if constexpr (BR) {
        float4 b = *reinterpret_cast<const float4*>(bias + cb);
        a0 = fmaxf(a0 + b.x, 0.f);
        a1 = fmaxf(a1 + b.y, 0.f);
        a2 = fmaxf(a2 + b.z, 0.f);
        a3 = fmaxf(a3 + b.w, 0.f);
    }
    if constexpr (PS) {
        float dv = dinv[r];
        a0 *= dv; a1 *= dv; a2 *= dv; a3 *= dv;
    }
    *reinterpret_cast<float4*>(&h[(size_t)r * F + cb]) = float4{a0, a1, a2, a3};
}

extern "C" void kernel_launch(void* const* d_in, const int* in_sizes, int n_in,
                              void* d_out, int out_size, void* d_ws, size_t ws_size,
                              hipStream_t stream) {
    const float* x = (const float*)d_in[0];
    const int* ei = (const int*)d_in[1];
    const float* W1 = (const float*)d_in[3];
    const float* b1 = (const float*)d_in[4];
    const float* W2 = (const float*)d_in[5];
    const float* b2 = (const float*)d_in[6];
    const float* W3 = (const float*)d_in[7];
    const float* b3 = (const float*)d_in[8];
    const float* W4 = (const float*)d_in[9];
    const float* b4 = (const float*)d_in[10];
    const float* W5 = (const float*)d_in[11];
    const float* b5 = (const float*)d_in[12];
    const float* Wl = (const float*)d_in[13];
    const float* bl = (const float*)d_in[14];

    const int N = in_sizes[0] / 2;
    const int E = in_sizes[1] / 2;
    const int* src = ei;
    const int* dst = ei + E;

    char* wp = (char*)d_ws;
    auto alloc = [&](size_t bytes) -> void* {
        void* p = wp;
        wp += ((bytes + 255) / 256) * 256;
        return p;
    };
    int* cnt = (int*)alloc((size_t)N * 4);
    int* off = (int*)alloc((size_t)(N + 1) * 4);
    int* cursor = (int*)alloc((size_t)N * 4);
    int* bsum = (int*)alloc(512 * 4);
    int* bpre = (int*)alloc(512 * 4);
    int* csr = (int*)alloc((size_t)E * 4);
    float* dinv = (float*)alloc((size_t)N * 4);
    float* xs2 = (float*)alloc((size_t)N * 2 * 4);
    float* t2 = (float*)alloc((size_t)N * 2 * 4);
    float* bufA = (float*)alloc((size_t)N * 128 * 4);
    float* bufB = (float*)alloc((size_t)N * 128 * 4);

    const int gN = cdiv(N, 256);
    const int gE = cdiv(E, 256);
    const int nb = gN;
    const int gT = cdiv(N, 64);

    // Ranged fill grid: 8 classes x 128 chunks.
    const int NCHUNK = 128;
    const int echunk = cdiv(E, NCHUNK);
    const int gR = 8 * NCHUNK;

    // XCD-sliced agg grids: 8 classes x node-groups of 32 (per dst-half).
    const int gX = 8 * cdiv((N + 1) / 2, 32);

    // --- CSR build ---
    zero_i32<<<gN, 256, 0, stream>>>(cnt, N);
    count_kernel<<<gE, 256, 0, stream>>>(dst, cnt, E);
    scan1<<<nb, 256, 0, stream>>>(cnt, off, bsum, N);
    scan2<<<1, 512, 0, stream>>>(bsum, bpre, nb, off, N, E);
    scan3_fused<<<nb, 256, 0, stream>>>(cnt, bpre, off, cursor, x, dinv, xs2, N);
    fill_ranged<<<gR, 256, 0, stream>>>(src, dst, cursor, csr, E, N, echunk);

    // --- Layer 1: agg pre-scaled [N,2], gemm 2->128 (+b1, relu, *dinv) ---
    agg2_kernel<<<gN, 256, 0, stream>>>(xs2, off, csr, dinv, t2, N);
    gemm_small<2, 128, true, true><<<cdiv(N, 8), 256, 0, stream>>>(t2, W1, b1, dinv, bufA, N);
    // --- Layer 2: gemm 128->128 (raw, cm32 out), agg128x (+b2, relu, *dinv) ---
    gemm_tiled<128, 128, false, false, 0, 32><<<gT, 256, 0, stream>>>(bufA, W2, nullptr, nullptr, bufB, N);
    agg128x_kernel<true, true><<<gX, 256, 0, stream>>>(bufB, off, csr, dinv, b2, bufA, N);
    // --- Layer 3: gemm 128->32 (cm32 in, cm8 out), agg32x (+b3, relu, *dinv) ---
    gemm_tiled<128, 32, false, false, 32, 8><<<gT, 256, 0, stream>>>(bufA, W3, nullptr, nullptr, bufB, N);
    agg32x_kernel<true, true><<<gX, 256, 0, stream>>>(bufB, off, csr, dinv, b3, bufA, N);
    // --- Layer 4: gemm 32->32 (cm8 in/out), agg32x (+b4, relu, *dinv) ---
    gemm_tiled<32, 32, false, false, 8, 8><<<gT, 256, 0, stream>>>(bufA, W4, nullptr, nullptr, bufB, N);
    agg32x_kernel<true, true><<<gX, 256, 0, stream>>>(bufB, off, csr, dinv, b4, bufA, N);
    // --- Layer 5: agg32x raw (cm8) -> fused gemm 32->64 + final 64->1 ---
    agg32x_kernel<false, false><<<gX, 256, 0, stream>>>(bufA, off, csr, dinv, nullptr, bufB, N);
    gemm_final<<<gT, 256, 0, stream>>>(bufB, W5, b5, Wl, bl, (float*)d_out, N);
}

// Round 3
// 526.175 us; speedup vs baseline: 1.0877x; 1.0877x over previous
//
#include <hip/hip_runtime.h>
#include <math.h>

// ---------------------------------------------------------------------------
// GCN 5-layer forward, dinv-prescaled formulation.
//   agg[v] = dinv[v] * ( sum_{s in N(v)} hs[s] + hs[v] ),  hs = dinv (.) h.
// Layer plan (narrow-side aggregation):
//   L1: agg2(xs=dinv*x) -> gemm 2->128 +b1 relu *dinv
//   L2: gemm 128->128 (cm32 out) ; agg128x +b2 relu *dinv (cm32)
//   L3: gemm 128->32 (cm32 in) ; agg32 +b3 relu *dinv
//   L4: gemm 32->32   ; agg32  +b4 relu *dinv
//   L5: agg32 raw     ; gemm_final: (t5@W5+b5).relu @ Wl + bl -> out
// R16: SRC-QUARTILE EDGE ORDERING (cache blocking by data order, not code):
//   csr stores each node's edges bucketed by src quartile. Agg kernels are
//   UNCHANGED (same instrs, same 128B granules) but their random gathers
//   sweep 4 temporal phases of ~1/4 working set each: agg128x class ws
//   12.8 -> ~3.2MB/phase (L2-resident), agg32 ws likewise. Implemented via
//   cntq[4N] count, 4-way prefix in scan3, cursorq[4N] in fill.
// R15 post-mortem (REVERTED): agg32x 8-col chunks made total +42us. agg32
//   trio is LATENCY/INSTRUCTION-bound (~2.5TB/s < 3.9 wall); 4x instruction
//   stream for fewer bytes = loss. Slicing only pays at the BW wall with
//   unchanged instruction count.
// R14 post-mortem: agg128x (cm32, 8 classes) 127->98us, FETCH 414->328MB.
//   12.8MB slice >> 4MB L2 caps hit at ~63%.
// R13 post-mortem: gemm_big128 spilled accumulators. REVERTED.
// Structural walls (measured): fill/count atomic floors; fp32 vector-ALU
//   gemms (no fp32 MFMA; bf16 blows the 7.9e-5 absmax budget).
// ---------------------------------------------------------------------------

static inline int cdiv(int a, int b) { return (a + b - 1) / b; }

__global__ void zero_i32(int* __restrict__ p, int n) {
    int i = blockIdx.x * 256 + threadIdx.x;
    if (i < n) p[i] = 0;
}

// Degree count per (dst, src-quartile): atomics into cntq[4N].
__global__ void count_q(const int* __restrict__ src, const int* __restrict__ dst,
                        int* __restrict__ cntq, int E, int q1) {
    int e = blockIdx.x * 256 + threadIdx.x;
    if (e < E) {
        int s = src[e];
        int q = (s >= q1) + (s >= 2 * q1) + (s >= 3 * q1);
        atomicAdd(&cntq[dst[e] * 4 + q], 1);
    }
}

// Inclusive scan per 256-block of per-node TOTALS (sum of 4 quartile counts);
// inclusive partials to off, block totals to bsum.
__global__ void scan1q(const int* __restrict__ cntq, int* __restrict__ off,
                       int* __restrict__ bsum, int n) {
    __shared__ int sm[256];
    int i = blockIdx.x * 256 + threadIdx.x;
    int v = 0;
    if (i < n) {
        int4 c = *reinterpret_cast<const int4*>(cntq + 4 * (size_t)i);
        v = c.x + c.y + c.z + c.w;
    }
    sm[threadIdx.x] = v;
    __syncthreads();
    for (int ofs = 1; ofs < 256; ofs <<= 1) {
        int t = (threadIdx.x >= (unsigned)ofs) ? sm[threadIdx.x - ofs] : 0;
        __syncthreads();
        sm[threadIdx.x] += t;
        __syncthreads();
    }
    if (i < n) off[i] = sm[threadIdx.x];
    if (threadIdx.x == 255) bsum[blockIdx.x] = sm[255];
}

// Exclusive scan of block sums (nb <= 512).
__global__ void scan2(const int* __restrict__ bsum, int* __restrict__ bpre,
                      int nb, int* __restrict__ off, int N, int E) {
    __shared__ int sm[512];
    int t = threadIdx.x;
    sm[t] = (t < nb) ? bsum[t] : 0;
    __syncthreads();
    for (int ofs = 1; ofs < 512; ofs <<= 1) {
        int v = (t >= ofs) ? sm[t - ofs] : 0;
        __syncthreads();
        sm[t] += v;
        __syncthreads();
    }
    if (t < nb) bpre[t] = sm[t] - bsum[t];
    if (t == 0) off[N] = E;
}

// Fused: finalize off (exclusive), seed 4 quartile cursors per node,
// dinv=1/sqrt(deg+1), xs = dinv * x.
__global__ void scan3_fused(const int* __restrict__ cntq, const int* __restrict__ bpre,
                            int* __restrict__ off, int* __restrict__ cursorq,
                            const float* __restrict__ x, float* __restrict__ dinv,
                            float* __restrict__ xs, int n) {
    int i = blockIdx.x * 256 + threadIdx.x;
    if (i < n) {
        int4 cq = *reinterpret_cast<const int4*>(cntq + 4 * (size_t)i);
        int c = cq.x + cq.y + cq.z + cq.w;
        int o = off[i] - c + bpre[blockIdx.x];
        off[i] = o;
        int4 cur;
        cur.x = o;
        cur.y = o + cq.x;
        cur.z = o + cq.x + cq.y;
        cur.w = o + cq.x + cq.y + cq.z;
        *reinterpret_cast<int4*>(cursorq + 4 * (size_t)i) = cur;
        float dv = 1.0f / sqrtf((float)c + 1.0f);
        dinv[i] = dv;
        float2 xv = *reinterpret_cast<const float2*>(x + 2 * (size_t)i);
        *reinterpret_cast<float2*>(xs + 2 * (size_t)i) = float2{dv * xv.x, dv * xv.y};
    }
}

// XCD-class-filtered CSR fill with src-quartile bucketing: class c handles
// only its dst-range (cursorq slice ~200KB, csr slice ~800KB stay in one
// XCD's L2). Each node's edge list lands as [q0|q1|q2|q3] segments.
__global__ __launch_bounds__(256) void fill_ranged(const int* __restrict__ src,
                                                   const int* __restrict__ dst,
                                                   int* __restrict__ cursorq,
                                                   int* __restrict__ csr,
                                                   int E, int N, int echunk, int q1) {
    int cls = blockIdx.x & 7;
    int chunk = blockIdx.x >> 3;
    int per = (N + 7) >> 3;
    int lo = cls * per;
    int hi = lo + per; if (hi > N) hi = N;
    int e0 = chunk * echunk;
    int e1 = e0 + echunk; if (e1 > E) e1 = E;
    for (int e = e0 + (int)threadIdx.x; e < e1; e += 256) {
        int d = dst[e];
        if (d >= lo && d < hi) {
            int s = src[e];
            int q = (s >= q1) + (s >= 2 * q1) + (s >= 3 * q1);
            int p = atomicAdd(&cursorq[d * 4 + q], 1);
            csr[p] = s;
        }
    }
}

// ---------------------------------------------------------------------------
// Aggregation of pre-scaled [N,2] input: one thread per node.
// ---------------------------------------------------------------------------
__global__ __launch_bounds__(256) void agg2_kernel(const float* __restrict__ xs,
                                                   const int* __restrict__ off,
                                                   const int* __restrict__ csr,
                                                   const float* __restrict__ dinv,
                                                   float* __restrict__ out, int n) {
    int v = blockIdx.x * 256 + threadIdx.x;
    if (v >= n) return;
    float a0 = 0.f, a1 = 0.f;
    int e0 = off[v], e1 = off[v + 1];
    for (int e = e0; e < e1; e++) {
        int s = csr[e];
        float2 q = *reinterpret_cast<const float2*>(xs + 2 * (size_t)s);
        a0 += q.x;
        a1 += q.y;
    }
    float dv = dinv[v];
    float2 xv = *reinterpret_cast<const float2*>(xs + 2 * (size_t)v);
    *reinterpret_cast<float2*>(out + 2 * (size_t)v) =
        float2{dv * (a0 + xv.x), dv * (a1 + xv.y)};
}

// ---------------------------------------------------------------------------
// agg128x: F=128 aggregation, XCD-sliced. h is chunk-major hc[4][N][32].
// class = blockIdx&7: chunk = cls>>1 (32-col slice), half = cls&1 (dst half).
// With src-quartile edge order, per-phase gather ws = 3.2MB (L2-resident).
// ---------------------------------------------------------------------------
template <bool BR, bool PS>
__global__ __launch_bounds__(256) void agg128x_kernel(const float* __restrict__ hc,
                                                      const int* __restrict__ off,
                                                      const int* __restrict__ csr,
                                                      const float* __restrict__ dinv,
                                                      const float* __restrict__ bias,
                                                      float* __restrict__ outc, int n) {
    int cls = blockIdx.x & 7;
    int chunk = cls >> 1;
    int half = cls & 1;
    int n2 = (n + 1) >> 1;
    int lo = half * n2;
    int hi = lo + n2; if (hi > n) hi = n;

    const float* __restrict__ h = hc + (size_t)chunk * n * 32;
    float* __restrict__ out = outc + (size_t)chunk * n * 32;

    int tid = threadIdx.x;
    int lane = tid & 63;
    int sl = lane & 7;
    int subbase = lane & ~7;
    int wave = tid >> 6;
    int v = lo + (blockIdx.x >> 3) * 32 + wave * 8 + (lane >> 3);
    if (v >= hi) return;

    int start = off[v];
    int end = off[v + 1];

    float4 acc = {0.f, 0.f, 0.f, 0.f};

    for (int base = start; base < end; base += 16) {
        int m = end - base;
        if (m > 16) m = 16;
        int idxA = (sl < m) ? csr[base + sl] : 0;
        int idxB = (8 + sl < m) ? csr[base + 8 + sl] : 0;
        if (m == 16) {
            float4 hb[16];
#pragma unroll
            for (int u = 0; u < 16; u++) {
                int s = __shfl((u < 8) ? idxA : idxB, subbase + (u & 7));
                hb[u] = *reinterpret_cast<const float4*>(h + (size_t)s * 32 + sl * 4);
            }
#pragma unroll
            for (int u = 0; u < 16; u++) {
                acc.x += hb[u].x; acc.y += hb[u].y; acc.z += hb[u].z; acc.w += hb[u].w;
            }
        } else {
            int ma = (m < 8) ? m : 8;
            int i = 0;
            for (; i + 4 <= ma; i += 4) {
                float4 hb[4];
#pragma unroll
                for (int u = 0; u < 4; u++) {
                    int s = __shfl(idxA, subbase + i + u);
                    hb[u] = *reinterpret_cast<const float4*>(h + (size_t)s * 32 + sl * 4);
                }
#pragma unroll
                for (int u = 0; u < 4; u++) {
                    acc.x += hb[u].x; acc.y += hb[u].y; acc.z += hb[u].z; acc.w += hb[u].w;
                }
            }
            if (i + 2 <= ma) {
                int s0 = __shfl(idxA, subbase + i);
                int s1 = __shfl(idxA, subbase + i + 1);
                float4 h0 = *reinterpret_cast<const float4*>(h + (size_t)s0 * 32 + sl * 4);
                float4 h1 = *reinterpret_cast<const float4*>(h + (size_t)s1 * 32 + sl * 4);
                acc.x += h0.x + h1.x; acc.y += h0.y + h1.y;
                acc.z += h0.z + h1.z; acc.w += h0.w + h1.w;
                i += 2;
            }
            if (i < ma) {
                int s0 = __shfl(idxA, subbase + i);
                float4 h0 = *reinterpret_cast<const float4*>(h + (size_t)s0 * 32 + sl * 4);
                acc.x += h0.x; acc.y += h0.y; acc.z += h0.z; acc.w += h0.w;
            }
            if (m > 8) {
                int mb = m - 8;
                int j = 0;
                for (; j + 4 <= mb; j += 4) {
                    float4 hb[4];
#pragma unroll
                    for (int u = 0; u < 4; u++) {
                        int s = __shfl(idxB, subbase + j + u);
                        hb[u] = *reinterpret_cast<const float4*>(h + (size_t)s * 32 + sl * 4);
                    }
#pragma unroll
                    for (int u = 0; u < 4; u++) {
                        acc.x += hb[u].x; acc.y += hb[u].y; acc.z += hb[u].z; acc.w += hb[u].w;
                    }
                }
                if (j + 2 <= mb) {
                    int s0 = __shfl(idxB, subbase + j);
                    int s1 = __shfl(idxB, subbase + j + 1);
                    float4 h0 = *reinterpret_cast<const float4*>(h + (size_t)s0 * 32 + sl * 4);
                    float4 h1 = *reinterpret_cast<const float4*>(h + (size_t)s1 * 32 + sl * 4);
                    acc.x += h0.x + h1.x; acc.y += h0.y + h1.y;
                    acc.z += h0.z + h1.z; acc.w += h0.w + h1.w;
                    j += 2;
                }
                if (j < mb) {
                    int s0 = __shfl(idxB, subbase + j);
                    float4 h0 = *reinterpret_cast<const float4*>(h + (size_t)s0 * 32 + sl * 4);
                    acc.x += h0.x; acc.y += h0.y; acc.z += h0.z; acc.w += h0.w;
                }
            }
        }
    }

    float dv = dinv[v];
    float4 hv = *reinterpret_cast<const float4*>(h + (size_t)v * 32 + sl * 4);
    float o0 = dv * (acc.x + hv.x);
    float o1 = dv * (acc.y + hv.y);
    float o2 = dv * (acc.z + hv.z);
    float o3 = dv * (acc.w + hv.w);
    if constexpr (BR) {
        float4 b = *reinterpret_cast<const float4*>(bias + chunk * 32 + sl * 4);
        o0 = fmaxf(o0 + b.x, 0.f);
        o1 = fmaxf(o1 + b.y, 0.f);
        o2 = fmaxf(o2 + b.z, 0.f);
        o3 = fmaxf(o3 + b.w, 0.f);
    }
    if constexpr (PS) {
        o0 *= dv; o1 *= dv; o2 *= dv; o3 *= dv;
    }
    *reinterpret_cast<float4*>(out + (size_t)v * 32 + sl * 4) = float4{o0, o1, o2, o3};
}

// ---------------------------------------------------------------------------
// agg32: F=32, 8 lanes/node, lane owns 4 cols (float4). Dual 8-edge chunks.
// (R15 revert: row-major [N,32], one float4/lane/edge.)
// ---------------------------------------------------------------------------
template <bool BR, bool PS>
__global__ __launch_bounds__(256) void agg32_kernel(const float* __restrict__ h,
                                                    const int* __restrict__ off,
                                                    const int* __restrict__ csr,
                                                    const float* __restrict__ dinv,
                                                    const float* __restrict__ bias,
                                                    float* __restrict__ out, int n) {
    int tid = threadIdx.x;
    int lane = tid & 63;
    int sl = lane & 7;
    int subbase = lane & ~7;
    int wave = tid >> 6;
    int v = blockIdx.x * 32 + wave * 8 + (lane >> 3);
    if (v >= n) return;

    int start = off[v];
    int end = off[v + 1];

    float4 acc = {0.f, 0.f, 0.f, 0.f};

    for (int base = start; base < end; base += 16) {
        int m = end - base;
        if (m > 16) m = 16;
        int idxA = (sl < m) ? csr[base + sl] : 0;
        int idxB = (8 + sl < m) ? csr[base + 8 + sl] : 0;
        if (m == 16) {
            float4 hb[16];
#pragma unroll
            for (int u = 0; u < 16; u++) {
                int s = __shfl((u < 8) ? idxA : idxB, subbase + (u & 7));
                hb[u] = *reinterpret_cast<const float4*>(h + (size_t)s * 32 + sl * 4);
            }
#pragma unroll
            for (int u = 0; u < 16; u++) {
                acc.x += hb[u].x; acc.y += hb[u].y; acc.z += hb[u].z; acc.w += hb[u].w;
            }
        } else {
            int ma = (m < 8) ? m : 8;
            int i = 0;
            for (; i + 4 <= ma; i += 4) {
                float4 hb[4];
#pragma unroll
                for (int u = 0; u < 4; u++) {
                    int s = __shfl(idxA, subbase + i + u);
                    hb[u] = *reinterpret_cast<const float4*>(h + (size_t)s * 32 + sl * 4);
                }
#pragma unroll
                for (int u = 0; u < 4; u++) {
                    acc.x += hb[u].x; acc.y += hb[u].y; acc.z += hb[u].z; acc.w += hb[u].w;
                }
            }
            if (i + 2 <= ma) {
                int s0 = __shfl(idxA, subbase + i);
                int s1 = __shfl(idxA, subbase + i + 1);
                float4 h0 = *reinterpret_cast<const float4*>(h + (size_t)s0 * 32 + sl * 4);
                float4 h1 = *reinterpret_cast<const float4*>(h + (size_t)s1 * 32 + sl * 4);
                acc.x += h0.x + h1.x; acc.y += h0.y + h1.y;
                acc.z += h0.z + h1.z; acc.w += h0.w + h1.w;
                i += 2;
            }
            if (i < ma) {
                int s0 = __shfl(idxA, subbase + i);
                float4 h0 = *reinterpret_cast<const float4*>(h + (size_t)s0 * 32 + sl * 4);
                acc.x += h0.x; acc.y += h0.y; acc.z += h0.z; acc.w += h0.w;
            }
            if (m > 8) {
                int mb = m - 8;
                int j = 0;
                for (; j + 4 <= mb; j += 4) {
                    float4 hb[4];
#pragma unroll
                    for (int u = 0; u < 4; u++) {
                        int s = __shfl(idxB, subbase + j + u);
                        hb[u] = *reinterpret_cast<const float4*>(h + (size_t)s * 32 + sl * 4);
                    }
#pragma unroll
                    for (int u = 0; u < 4; u++) {
                        acc.x += hb[u].x; acc.y += hb[u].y; acc.z += hb[u].z; acc.w += hb[u].w;
                    }
                }
                if (j + 2 <= mb) {
                    int s0 = __shfl(idxB, subbase + j);
                    int s1 = __shfl(idxB, subbase + j + 1);
                    float4 h0 = *reinterpret_cast<const float4*>(h + (size_t)s0 * 32 + sl * 4);
                    float4 h1 = *reinterpret_cast<const float4*>(h + (size_t)s1 * 32 + sl * 4);
                    acc.x += h0.x + h1.x; acc.y += h0.y + h1.y;
                    acc.z += h0.z + h1.z; acc.w += h0.w + h1.w;
                    j += 2;
                }
                if (j < mb) {
                    int s0 = __shfl(idxB, subbase + j);
                    float4 h0 = *reinterpret_cast<const float4*>(h + (size_t)s0 * 32 + sl * 4);
                    acc.x += h0.x; acc.y += h0.y; acc.z += h0.z; acc.w += h0.w;
                }
            }
        }
    }

    float dv = dinv[v];
    float4 hv = *reinterpret_cast<const float4*>(h + (size_t)v * 32 + sl * 4);
    float o0 = dv * (acc.x + hv.x);
    float o1 = dv * (acc.y + hv.y);
    float o2 = dv * (acc.z + hv.z);
    float o3 = dv * (acc.w + hv.w);
    if constexpr (BR) {
        float4 b = *reinterpret_cast<const float4*>(bias + sl * 4);
        o0 = fmaxf(o0 + b.x, 0.f);
        o1 = fmaxf(o1 + b.y, 0.f);
        o2 = fmaxf(o2 + b.z, 0.f);
        o3 = fmaxf(o3 + b.w, 0.f);
    }
    if constexpr (PS) {
        o0 *= dv; o1 *= dv; o2 *= dv; o3 *= dv;
    }
    *reinterpret_cast<float4*>(out + (size_t)v * 32 + sl * 4) = float4{o0, o1, o2, o3};
}

// ---------------------------------------------------------------------------
// Register-tiled GEMM: h[N,F] = x[N,K] @ W[K,F]; epilogue +bias/relu (BR),
// *dinv[row] (PS). KC=32 (KCP=36 breaks pow-2 banks): K=128 -> 4 chunks,
// K=32 -> single chunk (2 barriers).
// CIN/COUT: 0 = row-major, 32 = chunk-major [F/32][N][32] (for agg128x).
// ---------------------------------------------------------------------------
template <int K, int F, bool BR, bool PS, int CIN = 0, int COUT = 0>
__global__ __launch_bounds__(256, 4) void gemm_tiled(const float* __restrict__ x,
                                                     const float* __restrict__ W,
                                                     const float* __restrict__ bias,
                                                     const float* __restrict__ dinv,
                                                     float* __restrict__ h, int n) {
    constexpr int KC = 32;
    constexpr int KCP = 36;             // padded row stride (144 B, 16B-aligned)
    constexpr int ROWS = 64;
    constexpr int TPC = F / 4;
    constexpr int RT = 256 / TPC;
    constexpr int RPT = ROWS / RT;
    static_assert(K % KC == 0, "K must be a multiple of 32");

    __shared__ float Ws[KC * F];
    __shared__ float Xs[ROWS * KCP];

    const int tid = threadIdx.x;
    const int cb = (tid % TPC) * 4;
    const int tr = tid / TPC;
    const int row0 = blockIdx.x * ROWS;

    float acc[RPT][4];
#pragma unroll
    for (int r = 0; r < RPT; r++)
#pragma unroll
        for (int j = 0; j < 4; j++) acc[r][j] = 0.f;

#pragma unroll 1
    for (int k0 = 0; k0 < K; k0 += KC) {
        __syncthreads();
        {
            // Stage x chunk: 64 rows x 32 cols; thread -> row tid>>2, 8 cols.
            int r = tid >> 2;
            int kk = (tid & 3) * 8;
            int gr = row0 + r;
            float4 v0 = {0.f, 0.f, 0.f, 0.f}, v1 = {0.f, 0.f, 0.f, 0.f};
            if (gr < n) {
                if constexpr (CIN == 32) {
                    const float* xb = x + (size_t)(k0 >> 5) * n * 32 + (size_t)gr * 32 + kk;
                    v0 = *reinterpret_cast<const float4*>(xb);
                    v1 = *reinterpret_cast<const float4*>(xb + 4);
                } else {
                    v0 = *reinterpret_cast<const float4*>(x + (size_t)gr * K + k0 + kk);
                    v1 = *reinterpret_cast<const float4*>(x + (size_t)gr * K + k0 + kk + 4);
                }
            }
            *reinterpret_cast<float4*>(&Xs[r * KCP + kk]) = v0;
            *reinterpret_cast<float4*>(&Xs[r * KCP + kk + 4]) = v1;
        }
        for (int i = tid; i < KC * F / 4; i += 256) {
            *reinterpret_cast<float4*>(&Ws[i * 4]) =
                *reinterpret_cast<const float4*>(W + (size_t)k0 * F + i * 4);
        }
        __syncthreads();

#pragma unroll 4
        for (int kk4 = 0; kk4 < KC; kk4 += 4) {
            float4 xr[RPT];
#pragma unroll
            for (int r = 0; r < RPT; r++)
                xr[r] = *reinterpret_cast<const float4*>(&Xs[(tr * RPT + r) * KCP + kk4]);
#pragma unroll
            for (int j = 0; j < 4; j++) {
                float4 w = *reinterpret_cast<const float4*>(&Ws[(kk4 + j) * F + cb]);
#pragma unroll
                for (int r = 0; r < RPT; r++) {
                    float xv = (j == 0) ? xr[r].x : (j == 1) ? xr[r].y
                             : (j == 2) ? xr[r].z : xr[r].w;
                    acc[r][0] += xv * w.x;
                    acc[r][1] += xv * w.y;
                    acc[r][2] += xv * w.z;
                    acc[r][3] += xv * w.w;
                }
            }
        }
    }

    float4 b = float4{0.f, 0.f, 0.f, 0.f};
    if constexpr (BR) b = *reinterpret_cast<const float4*>(bias + cb);
#pragma unroll
    for (int r = 0; r < RPT; r++) {
        int row = row0 + tr * RPT + r;
        if (row < n) {
            float o0 = acc[r][0], o1 = acc[r][1], o2 = acc[r][2], o3 = acc[r][3];
            if constexpr (BR) {
                o0 = fmaxf(o0 + b.x, 0.f);
                o1 = fmaxf(o1 + b.y, 0.f);
                o2 = fmaxf(o2 + b.z, 0.f);
                o3 = fmaxf(o3 + b.w, 0.f);
            }
            if constexpr (PS) {
                float dv = dinv[row];
                o0 *= dv; o1 *= dv; o2 *= dv; o3 *= dv;
            }
            if constexpr (COUT == 32) {
                float* hb = h + (size_t)(cb >> 5) * n * 32 + (size_t)row * 32 + (cb & 31);
                *reinterpret_cast<float4*>(hb) = float4{o0, o1, o2, o3};
            } else {
                *reinterpret_cast<float4*>(&h[(size_t)row * F + cb]) = float4{o0, o1, o2, o3};
            }
        }
    }
}

// ---------------------------------------------------------------------------
// Fused L5 + final: out[v] = relu(t5[v]@W5 + b5) . Wl + bl.  K=32, F=64.
// Single KC=32 chunk; row outputs in 16 lanes x 4 regs -> dot with Wl (LDS)
// then 4-step shfl-xor reduce; lane0-of-16 writes out[row].
// ---------------------------------------------------------------------------
__global__ __launch_bounds__(256, 4) void gemm_final(const float* __restrict__ x,
                                                     const float* __restrict__ W,
                                                     const float* __restrict__ bias,
                                                     const float* __restrict__ Wl,
                                                     const float* __restrict__ bl,
                                                     float* __restrict__ out, int n) {
    constexpr int K = 32, F = 64;
    constexpr int KC = 32;
    constexpr int KCP = 36;
    constexpr int ROWS = 64;
    constexpr int TPC = F / 4;          // 16
    constexpr int RT = 256 / TPC;       // 16
    constexpr int RPT = ROWS / RT;      // 4

    __shared__ float Ws[KC * F];
    __shared__ float Xs[ROWS * KCP];
    __shared__ float wl[F];

    const int tid = threadIdx.x;
    if (tid < F) wl[tid] = Wl[tid];
    const int cb = (tid % TPC) * 4;
    const int tr = tid / TPC;
    const int row0 = blockIdx.x * ROWS;

    float acc[RPT][4];
#pragma unroll
    for (int r = 0; r < RPT; r++)
#pragma unroll
        for (int j = 0; j < 4; j++) acc[r][j] = 0.f;

    {
        {
            int r = tid >> 2;
            int kk = (tid & 3) * 8;
            int gr = row0 + r;
            float4 v0 = {0.f, 0.f, 0.f, 0.f}, v1 = {0.f, 0.f, 0.f, 0.f};
            if (gr < n) {
                v0 = *reinterpret_cast<const float4*>(x + (size_t)gr * K + kk);
                v1 = *reinterpret_cast<const float4*>(x + (size_t)gr * K + kk + 4);
            }
            *reinterpret_cast<float4*>(&Xs[r * KCP + kk]) = v0;
            *reinterpret_cast<float4*>(&Xs[r * KCP + kk + 4]) = v1;
        }
        for (int i = tid; i < KC * F / 4; i += 256) {
            *reinterpret_cast<float4*>(&Ws[i * 4]) =
                *reinterpret_cast<const float4*>(W + i * 4);
        }
        __syncthreads();

#pragma unroll 4
        for (int kk4 = 0; kk4 < KC; kk4 += 4) {
            float4 xr[RPT];
#pragma unroll
            for (int r = 0; r < RPT; r++)
                xr[r] = *reinterpret_cast<const float4*>(&Xs[(tr * RPT + r) * KCP + kk4]);
#pragma unroll
            for (int j = 0; j < 4; j++) {
                float4 w = *reinterpret_cast<const float4*>(&Ws[(kk4 + j) * F + cb]);
#pragma unroll
                for (int r = 0; r < RPT; r++) {
                    float xv = (j == 0) ? xr[r].x : (j == 1) ? xr[r].y
                             : (j == 2) ? xr[r].z : xr[r].w;
                    acc[r][0] += xv * w.x;
                    acc[r][1] += xv * w.y;
                    acc[r][2] += xv * w.z;
                    acc[r][3] += xv * w.w;
                }
            }
        }
    }

    float4 b = *reinterpret_cast<const float4*>(bias + cb);
    float4 w = *reinterpret_cast<const float4*>(&wl[cb]);
    float blv = bl[0];
#pragma unroll
    for (int r = 0; r < RPT; r++) {
        int row = row0 + tr * RPT + r;
        float o0 = fmaxf(acc[r][0] + b.x, 0.f);
        float o1 = fmaxf(acc[r][1] + b.y, 0.f);
        float o2 = fmaxf(acc[r][2] + b.z, 0.f);
        float o3 = fmaxf(acc[r][3] + b.w, 0.f);
        float partial = o0 * w.x + o1 * w.y + o2 * w.z + o3 * w.w;
        partial += __shfl_xor(partial, 8, 16);
        partial += __shfl_xor(partial, 4, 16);
        partial += __shfl_xor(partial, 2, 16);
        partial += __shfl_xor(partial, 1, 16);
        if ((tid & 15) == 0 && row < n) out[row] = partial + blv;
    }
}

// Simple GEMM for K=2 (layer 1), epilogue +bias/relu (BR), *dinv (PS).
template <int K, int F, bool BR, bool PS>
__global__ __launch_bounds__(256, 4) void gemm_small(const float* __restrict__ x,
                                                     const float* __restrict__ W,
                                                     const float* __restrict__ bias,
                                                     const float* __restrict__ dinv,
                                                     float* __restrict__ h, int n) {
    constexpr int TPR = F / 4;
    constexpr int ROWS = 256 / TPR;
    __shared__ float Ws[K * F];
    for (int i = threadIdx.x; i < K * F; i += 256) Ws[i] = W[i];
    __syncthreads();

    int tid = threadIdx.x;
    int cb = (tid % TPR) * 4;
    int r = blockIdx.x * ROWS + tid / TPR;
    if (r >= n) return;

    const float* xr = x + (size_t)r * K;
    float a0 = 0.f, a1 = 0.f, a2 = 0.f, a3 = 0.f;
#pragma unroll
    for (int k = 0; k < K; k++) {
        float xv = xr[k];
        float4 w = *reinterpret_cast<const float4*>(&Ws[k * F + cb]);
        a0 += xv * w.x; a1 += xv * w.y; a2 += xv * w.z; a3 += xv * w.w;
    }
    if constexpr (BR) {
        float4 b = *reinterpret_cast<const float4*>(bias + cb);
        a0 = fmaxf(a0 + b.x, 0.f);
        a1 = fmaxf(a1 + b.y, 0.f);
        a2 = fmaxf(a2 + b.z, 0.f);
        a3 = fmaxf(a3 + b.w, 0.f);
    }
    if constexpr (PS) {
        float dv = dinv[r];
        a0 *= dv; a1 *= dv; a2 *= dv; a3 *= dv;
    }
    *reinterpret_cast<float4*>(&h[(size_t)r * F + cb]) = float4{a0, a1, a2, a3};
}

extern "C" void kernel_launch(void* const* d_in, const int* in_sizes, int n_in,
                              void* d_out, int out_size, void* d_ws, size_t ws_size,
                              hipStream_t stream) {
    const float* x = (const float*)d_in[0];
    const int* ei = (const int*)d_in[1];
    const float* W1 = (const float*)d_in[3];
    const float* b1 = (const float*)d_in[4];
    const float* W2 = (const float*)d_in[5];
    const float* b2 = (const float*)d_in[6];
    const float* W3 = (const float*)d_in[7];
    const float* b3 = (const float*)d_in[8];
    const float* W4 = (const float*)d_in[9];
    const float* b4 = (const float*)d_in[10];
    const float* W5 = (const float*)d_in[11];
    const float* b5 = (const float*)d_in[12];
    const float* Wl = (const float*)d_in[13];
    const float* bl = (const float*)d_in[14];

    const int N = in_sizes[0] / 2;
    const int E = in_sizes[1] / 2;
    const int* src = ei;
    const int* dst = ei + E;

    char* wp = (char*)d_ws;
    auto alloc = [&](size_t bytes) -> void* {
        void* p = wp;
        wp += ((bytes + 255) / 256) * 256;
        return p;
    };
    int* cntq = (int*)alloc((size_t)N * 4 * 4);
    int* off = (int*)alloc((size_t)(N + 1) * 4);
    int* cursorq = (int*)alloc((size_t)N * 4 * 4);
    int* bsum = (int*)alloc(512 * 4);
    int* bpre = (int*)alloc(512 * 4);
    int* csr = (int*)alloc((size_t)E * 4);
    float* dinv = (float*)alloc((size_t)N * 4);
    float* xs2 = (float*)alloc((size_t)N * 2 * 4);
    float* t2 = (float*)alloc((size_t)N * 2 * 4);
    float* bufA = (float*)alloc((size_t)N * 128 * 4);
    float* bufB = (float*)alloc((size_t)N * 128 * 4);

    const int gN = cdiv(N, 256);
    const int gE = cdiv(E, 256);
    const int nb = gN;
    const int gT = cdiv(N, 64);
    const int q1 = (N + 3) / 4;         // src quartile width

    // Ranged fill grid: 8 classes x 128 chunks.
    const int NCHUNK = 128;
    const int echunk = cdiv(E, NCHUNK);
    const int gR = 8 * NCHUNK;

    // agg128x grid: 8 classes (4 chunks x 2 dst-halves) x node-groups of 32.
    const int gX = 8 * cdiv((N + 1) / 2, 32);

    // --- CSR build (src-quartile-bucketed edge order) ---
    zero_i32<<<cdiv(4 * N, 256), 256, 0, stream>>>(cntq, 4 * N);
    count_q<<<gE, 256, 0, stream>>>(src, dst, cntq, E, q1);
    scan1q<<<nb, 256, 0, stream>>>(cntq, off, bsum, N);
    scan2<<<1, 512, 0, stream>>>(bsum, bpre, nb, off, N, E);
    scan3_fused<<<nb, 256, 0, stream>>>(cntq, bpre, off, cursorq, x, dinv, xs2, N);
    fill_ranged<<<gR, 256, 0, stream>>>(src, dst, cursorq, csr, E, N, echunk, q1);

    // --- Layer 1: agg pre-scaled [N,2], gemm 2->128 (+b1, relu, *dinv) ---
    agg2_kernel<<<gN, 256, 0, stream>>>(xs2, off, csr, dinv, t2, N);
    gemm_small<2, 128, true, true><<<cdiv(N, 8), 256, 0, stream>>>(t2, W1, b1, dinv, bufA, N);
    // --- Layer 2: gemm 128->128 (raw, cm32 out), agg128x (+b2, relu, *dinv) ---
    gemm_tiled<128, 128, false, false, 0, 32><<<gT, 256, 0, stream>>>(bufA, W2, nullptr, nullptr, bufB, N);
    agg128x_kernel<true, true><<<gX, 256, 0, stream>>>(bufB, off, csr, dinv, b2, bufA, N);
    // --- Layer 3: gemm 128->32 (cm32 in), agg32 (+b3, relu, *dinv) ---
    gemm_tiled<128, 32, false, false, 32, 0><<<gT, 256, 0, stream>>>(bufA, W3, nullptr, nullptr, bufB, N);
    agg32_kernel<true, true><<<cdiv(N, 32), 256, 0, stream>>>(bufB, off, csr, dinv, b3, bufA, N);
    // --- Layer 4: gemm 32->32, agg32 (+b4, relu, *dinv) ---
    gemm_tiled<32, 32, false, false, 0, 0><<<gT, 256, 0, stream>>>(bufA, W4, nullptr, nullptr, bufB, N);
    agg32_kernel<true, true><<<cdiv(N, 32), 256, 0, stream>>>(bufB, off, csr, dinv, b4, bufA, N);
    // --- Layer 5: agg32 raw -> A_hat x4, fused gemm 32->64 + final 64->1 ---
    agg32_kernel<false, false><<<cdiv(N, 32), 256, 0, stream>>>(bufA, off, csr, dinv, nullptr, bufB, N);
    gemm_final<<<gT, 256, 0, stream>>>(bufB, W5, b5, Wl, bl, (float*)d_out, N);
}